// Round 1
// baseline (2017.225 us; speedup 1.0000x reference)
//
#include <hip/hip_runtime.h>

#define DECAY 0.99f
#define ONE_MINUS_DECAY 0.01f
#define EPSF 1e-5f
#define BETA 0.25f

constexpr int Bb = 32, Cc = 128, Hh = 32, Ww = 32;
constexpr int M_ = Bb * Hh * Ww;     // 32768 rows
constexpr int N_ = 1024;             // codes
constexpr int K_ = 128;              // dim
constexpr int SPLITS = 16;
constexpr int CPS = N_ / SPLITS;     // 64 codes per split

// ---- workspace layout (bytes) ----
constexpr size_t WS_FLAT   = 0;                                  // M_*K_ floats (16 MB)
constexpr size_t WS_PSCORE = WS_FLAT   + (size_t)M_ * K_ * 4;    // SPLITS*M_ floats
constexpr size_t WS_PIDX   = WS_PSCORE + (size_t)SPLITS * M_ * 4;
constexpr size_t WS_IDX    = WS_PIDX   + (size_t)SPLITS * M_ * 4; // M_ ints
constexpr size_t WS_ENORM  = WS_IDX    + (size_t)M_ * 4;         // N_ floats
constexpr size_t WS_COUNTS = WS_ENORM  + (size_t)N_ * 4;         // N_ ints      (zeroed)
constexpr size_t WS_ESUM   = WS_COUNTS + (size_t)N_ * 4;         // N_*K_ floats (zeroed)
constexpr size_t WS_LOSS   = WS_ESUM   + (size_t)N_ * K_ * 4;    // 1 double     (zeroed)
constexpr size_t WS_NSUM   = WS_LOSS   + 16;                     // 1 float (written each call)
constexpr size_t ZERO_OFF  = WS_COUNTS;
constexpr size_t ZERO_LEN  = WS_NSUM + 16 - WS_COUNTS;

// ---- output layout (float elements) ----
constexpr size_t O_ZQST = 0;
constexpr size_t O_LOSS = O_ZQST + (size_t)M_ * K_;   // 4194304
constexpr size_t O_IDX  = O_LOSS + 1;
constexpr size_t O_ZQ   = O_IDX  + (size_t)M_;
constexpr size_t O_ZE   = O_ZQ   + (size_t)M_ * K_;
constexpr size_t O_EMB  = O_ZE   + (size_t)M_ * K_;
constexpr size_t O_NCS  = O_EMB  + (size_t)N_ * K_;
constexpr size_t O_NEA  = O_NCS  + (size_t)N_;

// ||e_j||^2
__global__ void enorm_kernel(const float* __restrict__ embed, float* __restrict__ enorm) {
    int j = blockIdx.x;
    int lane = threadIdx.x;                    // 64 threads
    const float* e = embed + (size_t)j * K_;
    float a = e[lane], b = e[lane + 64];
    float s = a * a + b * b;
    #pragma unroll
    for (int off = 32; off; off >>= 1) s += __shfl_down(s, off);
    if (lane == 0) enorm[j] = s;
}

// (B,C,H,W) -> flat[r=b*1024+h*32+w][c], plus z_e passthrough output
__global__ void transpose_kernel(const float* __restrict__ ze,
                                 float* __restrict__ flat,
                                 float* __restrict__ out_ze) {
    __shared__ float tile[128][33];            // +1 pad breaks bank conflicts
    int b = blockIdx.x >> 5, h = blockIdx.x & 31;
    const size_t base = (size_t)b * 131072 + (size_t)h * 32;
    int t = threadIdx.x;                       // 256 threads
    #pragma unroll
    for (int i = 0; i < 16; ++i) {
        int q = i * 256 + t;                   // 4096 elements: c=q>>5, w=q&31
        int c = q >> 5, w = q & 31;
        float v = ze[base + (size_t)c * 1024 + w];
        tile[c][w] = v;
        out_ze[base + (size_t)c * 1024 + w] = v;
    }
    __syncthreads();
    float* dst = flat + ((size_t)b * 1024 + (size_t)h * 32) * K_;
    #pragma unroll
    for (int i = 0; i < 16; ++i) {
        int q = i * 256 + t;                   // c=q&127 contiguous per lane
        int c = q & 127, w = q >> 7;
        dst[(size_t)w * K_ + c] = tile[c][w];
    }
}

// NN search: thread-per-row, 64-code LDS chunk, 16 code-splits across blockIdx.y
__global__ void nn_kernel(const float* __restrict__ flat,
                          const float* __restrict__ embed,
                          const float* __restrict__ enorm,
                          float* __restrict__ pscore, int* __restrict__ pidx) {
    __shared__ float elds[CPS * K_];           // 32 KB
    __shared__ float nlds[CPS];
    const int split = blockIdx.y;
    const int c0 = split * CPS;
    const int t = threadIdx.x;                 // 256 threads

    const float4* esrc = (const float4*)(embed + (size_t)c0 * K_);
    float4* edst = (float4*)elds;
    #pragma unroll
    for (int i = 0; i < 8; ++i) edst[i * 256 + t] = esrc[i * 256 + t]; // 2048 float4
    if (t < CPS) nlds[t] = enorm[c0 + t];
    __syncthreads();

    const int r = blockIdx.x * 256 + t;
    const float4* xsrc = (const float4*)(flat + (size_t)r * K_);
    float4 x[32];
    #pragma unroll
    for (int i = 0; i < 32; ++i) x[i] = xsrc[i];

    float best = 3.4e38f;
    int bestj = c0;
    for (int j = 0; j < CPS; ++j) {
        const float4* ej = (const float4*)(elds + j * K_);  // wave-uniform -> broadcast
        float d0 = 0.f, d1 = 0.f, d2 = 0.f, d3 = 0.f;
        #pragma unroll
        for (int k = 0; k < 32; ++k) {
            float4 e4 = ej[k];
            d0 = fmaf(x[k].x, e4.x, d0);
            d1 = fmaf(x[k].y, e4.y, d1);
            d2 = fmaf(x[k].z, e4.z, d2);
            d3 = fmaf(x[k].w, e4.w, d3);
        }
        float s = fmaf(-2.f, (d0 + d1) + (d2 + d3), nlds[j]);
        if (s < best) { best = s; bestj = c0 + j; }   // strict < : first-min wins
    }
    pscore[(size_t)split * M_ + r] = best;
    pidx[(size_t)split * M_ + r] = bestj;
}

__global__ void reduce_idx_kernel(const float* __restrict__ pscore,
                                  const int* __restrict__ pidx,
                                  int* __restrict__ idxws, float* __restrict__ out_idx) {
    int r = blockIdx.x * 256 + threadIdx.x;
    float best = pscore[r];
    int bj = pidx[r];
    #pragma unroll
    for (int s = 1; s < SPLITS; ++s) {
        float v = pscore[(size_t)s * M_ + r];
        int j = pidx[(size_t)s * M_ + r];
        if (v < best) { best = v; bj = j; }   // ascending split => first-min wins
    }
    idxws[r] = bj;
    out_idx[r] = (float)bj;
}

// output-layout gather: z_q_st, z_q, loss partials
__global__ void gather_kernel(const float* __restrict__ ze,
                              const float* __restrict__ embed,
                              const int* __restrict__ idxws,
                              float* __restrict__ out_st, float* __restrict__ out_zq,
                              double* __restrict__ loss_acc) {
    int o = blockIdx.x * 256 + threadIdx.x;
    int w = o & 31, h = (o >> 5) & 31, c = (o >> 10) & 127, b = o >> 17;
    int r = b * 1024 + h * 32 + w;
    int j = idxws[r];
    float zq = embed[(size_t)j * K_ + c];
    float zev = ze[o];
    float st = zev + (zq - zev);              // match reference rounding
    out_st[o] = st;
    out_zq[o] = zq;
    float diff = st - zev;
    __shared__ double red[256];
    red[threadIdx.x] = (double)diff * (double)diff;
    __syncthreads();
    for (int s = 128; s; s >>= 1) {
        if (threadIdx.x < s) red[threadIdx.x] += red[threadIdx.x + s];
        __syncthreads();
    }
    if (threadIdx.x == 0) atomicAdd(loss_acc, red[0]);
}

// embed_sum scatter + counts
__global__ void scatter_kernel(const float* __restrict__ flat,
                               const int* __restrict__ idxws,
                               float* __restrict__ esum, int* __restrict__ counts) {
    int o = blockIdx.x * 256 + threadIdx.x;
    int r = o >> 7, k = o & 127;
    int j = idxws[r];
    atomicAdd(esum + (size_t)j * K_ + k, flat[o]);
    if (k == 0) atomicAdd(counts + j, 1);
}

__global__ void ema_a_kernel(const float* __restrict__ cluster_size,
                             const int* __restrict__ counts,
                             float* __restrict__ out_ncs, float* __restrict__ nws,
                             const double* __restrict__ loss_acc, float* __restrict__ out_loss) {
    int j = threadIdx.x;                       // 1024 threads
    float ncs = cluster_size[j] * DECAY + ONE_MINUS_DECAY * (float)counts[j];
    out_ncs[j] = ncs;
    __shared__ float red[1024];
    red[j] = ncs;
    __syncthreads();
    for (int s = 512; s; s >>= 1) {
        if (j < s) red[j] += red[j + s];
        __syncthreads();
    }
    if (j == 0) {
        nws[0] = red[0];
        out_loss[0] = (float)((double)BETA * (loss_acc[0] / 4194304.0));
    }
}

__global__ void ema_b_kernel(const float* __restrict__ embed_avg,
                             const float* __restrict__ esum,
                             const float* __restrict__ out_ncs,
                             const float* __restrict__ nws,
                             float* __restrict__ out_nea, float* __restrict__ out_emb) {
    int o = blockIdx.x * 256 + threadIdx.x;
    int j = o >> 7;
    float navg = embed_avg[o] * DECAY + ONE_MINUS_DECAY * esum[o];
    out_nea[o] = navg;
    float n = nws[0];
    float denom = n + 1024.0f * EPSF;
    float cs = (out_ncs[j] + EPSF) / denom * n;
    float cs_safe = fmaxf(cs, EPSF);
    float v = navg / cs_safe;
    if (v != v) v = 0.f;                       // nan_to_num
    v = fminf(fmaxf(v, -2.f), 2.f);            // clip
    out_emb[o] = v;
}

extern "C" void kernel_launch(void* const* d_in, const int* in_sizes, int n_in,
                              void* d_out, int out_size, void* d_ws, size_t ws_size,
                              hipStream_t stream) {
    const float* z_e          = (const float*)d_in[0];
    const float* embed        = (const float*)d_in[1];
    const float* cluster_size = (const float*)d_in[2];
    const float* embed_avg    = (const float*)d_in[3];
    float* out = (float*)d_out;
    char*  ws  = (char*)d_ws;

    float*  flat    = (float*)(ws + WS_FLAT);
    float*  pscore  = (float*)(ws + WS_PSCORE);
    int*    pidx    = (int*)  (ws + WS_PIDX);
    int*    idxws   = (int*)  (ws + WS_IDX);
    float*  enorm   = (float*)(ws + WS_ENORM);
    int*    counts  = (int*)  (ws + WS_COUNTS);
    float*  esum    = (float*)(ws + WS_ESUM);
    double* lossacc = (double*)(ws + WS_LOSS);
    float*  nws     = (float*)(ws + WS_NSUM);

    hipMemsetAsync(ws + ZERO_OFF, 0, ZERO_LEN, stream);

    enorm_kernel<<<N_, 64, 0, stream>>>(embed, enorm);
    transpose_kernel<<<Bb * Hh, 256, 0, stream>>>(z_e, flat, out + O_ZE);
    nn_kernel<<<dim3(M_ / 256, SPLITS), 256, 0, stream>>>(flat, embed, enorm, pscore, pidx);
    reduce_idx_kernel<<<M_ / 256, 256, 0, stream>>>(pscore, pidx, idxws, out + O_IDX);
    gather_kernel<<<(M_ * K_) / 256, 256, 0, stream>>>(z_e, embed, idxws,
                                                       out + O_ZQST, out + O_ZQ, lossacc);
    scatter_kernel<<<(M_ * K_) / 256, 256, 0, stream>>>(flat, idxws, esum, counts);
    ema_a_kernel<<<1, 1024, 0, stream>>>(cluster_size, counts, out + O_NCS, nws,
                                         lossacc, out + O_LOSS);
    ema_b_kernel<<<(N_ * K_) / 256, 256, 0, stream>>>(embed_avg, esum, out + O_NCS, nws,
                                                      out + O_NEA, out + O_EMB);
}

// Round 2
// 473.895 us; speedup vs baseline: 4.2567x; 4.2567x over previous
//
#include <hip/hip_runtime.h>

#define DECAY 0.99f
#define ONE_MINUS_DECAY 0.01f
#define EPSF 1e-5f
#define BETA 0.25f

constexpr int Bb = 32, Cc = 128, Hh = 32, Ww = 32;
constexpr int M_ = Bb * Hh * Ww;     // 32768 rows
constexpr int N_ = 1024;             // codes
constexpr int K_ = 128;              // dim
constexpr int SPLITS = 4;
constexpr int CPS = N_ / SPLITS;     // 256 codes per split
constexpr int CHUNK = 64;            // codes staged per LDS chunk

// ---- workspace layout (bytes) ----
constexpr size_t WS_FLAT   = 0;                                  // M_*K_ floats (16 MB)
constexpr size_t WS_PSCORE = WS_FLAT   + (size_t)M_ * K_ * 4;    // SPLITS*M_ floats
constexpr size_t WS_PIDX   = WS_PSCORE + (size_t)SPLITS * M_ * 4;
constexpr size_t WS_IDX    = WS_PIDX   + (size_t)SPLITS * M_ * 4; // M_ ints
constexpr size_t WS_ENORM  = WS_IDX    + (size_t)M_ * 4;         // N_ floats
constexpr size_t WS_COUNTS = WS_ENORM  + (size_t)N_ * 4;         // N_ ints      (zeroed)
constexpr size_t WS_ESUM   = WS_COUNTS + (size_t)N_ * 4;         // N_*K_ floats (zeroed)
constexpr size_t WS_LOSS   = WS_ESUM   + (size_t)N_ * K_ * 4;    // 1 double     (zeroed)
constexpr size_t WS_NSUM   = WS_LOSS   + 16;                     // 1 float (written each call)
constexpr size_t ZERO_OFF  = WS_COUNTS;
constexpr size_t ZERO_LEN  = WS_NSUM + 16 - WS_COUNTS;

// ---- output layout (float elements) ----
constexpr size_t O_ZQST = 0;
constexpr size_t O_LOSS = O_ZQST + (size_t)M_ * K_;   // 4194304
constexpr size_t O_IDX  = O_LOSS + 1;
constexpr size_t O_ZQ   = O_IDX  + (size_t)M_;
constexpr size_t O_ZE   = O_ZQ   + (size_t)M_ * K_;
constexpr size_t O_EMB  = O_ZE   + (size_t)M_ * K_;
constexpr size_t O_NCS  = O_EMB  + (size_t)N_ * K_;
constexpr size_t O_NEA  = O_NCS  + (size_t)N_;

// ||e_j||^2
__global__ void enorm_kernel(const float* __restrict__ embed, float* __restrict__ enorm) {
    int j = blockIdx.x;
    int lane = threadIdx.x;                    // 64 threads
    const float* e = embed + (size_t)j * K_;
    float a = e[lane], b = e[lane + 64];
    float s = a * a + b * b;
    #pragma unroll
    for (int off = 32; off; off >>= 1) s += __shfl_down(s, off);
    if (lane == 0) enorm[j] = s;
}

// (B,C,H,W) -> flat[r=b*1024+h*32+w][c], plus z_e passthrough output
__global__ void transpose_kernel(const float* __restrict__ ze,
                                 float* __restrict__ flat,
                                 float* __restrict__ out_ze) {
    __shared__ float tile[128][33];            // +1 pad breaks bank conflicts
    int b = blockIdx.x >> 5, h = blockIdx.x & 31;
    const size_t base = (size_t)b * 131072 + (size_t)h * 32;
    int t = threadIdx.x;                       // 256 threads
    #pragma unroll
    for (int i = 0; i < 16; ++i) {
        int q = i * 256 + t;                   // 4096 elements: c=q>>5, w=q&31
        int c = q >> 5, w = q & 31;
        float v = ze[base + (size_t)c * 1024 + w];
        tile[c][w] = v;
        out_ze[base + (size_t)c * 1024 + w] = v;
    }
    __syncthreads();
    float* dst = flat + ((size_t)b * 1024 + (size_t)h * 32) * K_;
    #pragma unroll
    for (int i = 0; i < 16; ++i) {
        int q = i * 256 + t;                   // c=q&127 contiguous per lane
        int c = q & 127, w = q >> 7;
        dst[(size_t)w * K_ + c] = tile[c][w];
    }
}

// NN search: thread-per-row with the row held in VGPRs.
// __launch_bounds__(256,1) lifts the default VGPR cap (64) that spilled
// x[32] to scratch in round 1 (6.4 GB scratch traffic, 25x slowdown).
__global__ __launch_bounds__(256, 1)
void nn_kernel(const float* __restrict__ flat,
               const float* __restrict__ embed,
               const float* __restrict__ enorm,
               float* __restrict__ pscore, int* __restrict__ pidx) {
    __shared__ float elds[CHUNK * K_];         // 32 KB
    __shared__ float nlds[CHUNK];
    const int split = blockIdx.y;
    const int t = threadIdx.x;                 // 256 threads
    const int r = blockIdx.x * 256 + t;

    const float4* xsrc = (const float4*)(flat + (size_t)r * K_);
    float4 x[32];                              // 128 VGPRs: the whole row
    #pragma unroll
    for (int i = 0; i < 32; ++i) x[i] = xsrc[i];

    float best = 3.4e38f;
    int bestj = split * CPS;
    for (int cc = 0; cc < CPS / CHUNK; ++cc) {
        const int c0 = split * CPS + cc * CHUNK;
        __syncthreads();                       // elds safe to overwrite
        const float4* esrc = (const float4*)(embed + (size_t)c0 * K_);
        float4* edst = (float4*)elds;
        #pragma unroll
        for (int i = 0; i < 8; ++i) edst[i * 256 + t] = esrc[i * 256 + t];
        if (t < CHUNK) nlds[t] = enorm[c0 + t];
        __syncthreads();
        for (int j = 0; j < CHUNK; ++j) {
            const float4* ej = (const float4*)(elds + j * K_);  // wave-uniform -> broadcast
            float d0 = 0.f, d1 = 0.f, d2 = 0.f, d3 = 0.f;
            #pragma unroll
            for (int k = 0; k < 32; ++k) {
                float4 e4 = ej[k];
                d0 = fmaf(x[k].x, e4.x, d0);
                d1 = fmaf(x[k].y, e4.y, d1);
                d2 = fmaf(x[k].z, e4.z, d2);
                d3 = fmaf(x[k].w, e4.w, d3);
            }
            float s = fmaf(-2.f, (d0 + d1) + (d2 + d3), nlds[j]);
            if (s < best) { best = s; bestj = c0 + j; }   // strict < : first-min wins
        }
    }
    pscore[(size_t)split * M_ + r] = best;
    pidx[(size_t)split * M_ + r] = bestj;
}

__global__ void reduce_idx_kernel(const float* __restrict__ pscore,
                                  const int* __restrict__ pidx,
                                  int* __restrict__ idxws, float* __restrict__ out_idx) {
    int r = blockIdx.x * 256 + threadIdx.x;
    float best = pscore[r];
    int bj = pidx[r];
    #pragma unroll
    for (int s = 1; s < SPLITS; ++s) {
        float v = pscore[(size_t)s * M_ + r];
        int j = pidx[(size_t)s * M_ + r];
        if (v < best) { best = v; bj = j; }   // ascending split => first-min wins
    }
    idxws[r] = bj;
    out_idx[r] = (float)bj;
}

// output-layout gather: z_q_st, z_q, loss partials
__global__ void gather_kernel(const float* __restrict__ ze,
                              const float* __restrict__ embed,
                              const int* __restrict__ idxws,
                              float* __restrict__ out_st, float* __restrict__ out_zq,
                              double* __restrict__ loss_acc) {
    int o = blockIdx.x * 256 + threadIdx.x;
    int w = o & 31, h = (o >> 5) & 31, c = (o >> 10) & 127, b = o >> 17;
    int r = b * 1024 + h * 32 + w;
    int j = idxws[r];
    float zq = embed[(size_t)j * K_ + c];
    float zev = ze[o];
    float st = zev + (zq - zev);              // match reference rounding
    out_st[o] = st;
    out_zq[o] = zq;
    float diff = st - zev;
    __shared__ double red[256];
    red[threadIdx.x] = (double)diff * (double)diff;
    __syncthreads();
    for (int s = 128; s; s >>= 1) {
        if (threadIdx.x < s) red[threadIdx.x] += red[threadIdx.x + s];
        __syncthreads();
    }
    if (threadIdx.x == 0) atomicAdd(loss_acc, red[0]);
}

// embed_sum scatter + counts
__global__ void scatter_kernel(const float* __restrict__ flat,
                               const int* __restrict__ idxws,
                               float* __restrict__ esum, int* __restrict__ counts) {
    int o = blockIdx.x * 256 + threadIdx.x;
    int r = o >> 7, k = o & 127;
    int j = idxws[r];
    atomicAdd(esum + (size_t)j * K_ + k, flat[o]);
    if (k == 0) atomicAdd(counts + j, 1);
}

__global__ void ema_a_kernel(const float* __restrict__ cluster_size,
                             const int* __restrict__ counts,
                             float* __restrict__ out_ncs, float* __restrict__ nws,
                             const double* __restrict__ loss_acc, float* __restrict__ out_loss) {
    int j = threadIdx.x;                       // 1024 threads
    float ncs = cluster_size[j] * DECAY + ONE_MINUS_DECAY * (float)counts[j];
    out_ncs[j] = ncs;
    __shared__ float red[1024];
    red[j] = ncs;
    __syncthreads();
    for (int s = 512; s; s >>= 1) {
        if (j < s) red[j] += red[j + s];
        __syncthreads();
    }
    if (j == 0) {
        nws[0] = red[0];
        out_loss[0] = (float)((double)BETA * (loss_acc[0] / 4194304.0));
    }
}

__global__ void ema_b_kernel(const float* __restrict__ embed_avg,
                             const float* __restrict__ esum,
                             const float* __restrict__ out_ncs,
                             const float* __restrict__ nws,
                             float* __restrict__ out_nea, float* __restrict__ out_emb) {
    int o = blockIdx.x * 256 + threadIdx.x;
    int j = o >> 7;
    float navg = embed_avg[o] * DECAY + ONE_MINUS_DECAY * esum[o];
    out_nea[o] = navg;
    float n = nws[0];
    float denom = n + 1024.0f * EPSF;
    float cs = (out_ncs[j] + EPSF) / denom * n;
    float cs_safe = fmaxf(cs, EPSF);
    float v = navg / cs_safe;
    if (v != v) v = 0.f;                       // nan_to_num
    v = fminf(fmaxf(v, -2.f), 2.f);            // clip
    out_emb[o] = v;
}

extern "C" void kernel_launch(void* const* d_in, const int* in_sizes, int n_in,
                              void* d_out, int out_size, void* d_ws, size_t ws_size,
                              hipStream_t stream) {
    const float* z_e          = (const float*)d_in[0];
    const float* embed        = (const float*)d_in[1];
    const float* cluster_size = (const float*)d_in[2];
    const float* embed_avg    = (const float*)d_in[3];
    float* out = (float*)d_out;
    char*  ws  = (char*)d_ws;

    float*  flat    = (float*)(ws + WS_FLAT);
    float*  pscore  = (float*)(ws + WS_PSCORE);
    int*    pidx    = (int*)  (ws + WS_PIDX);
    int*    idxws   = (int*)  (ws + WS_IDX);
    float*  enorm   = (float*)(ws + WS_ENORM);
    int*    counts  = (int*)  (ws + WS_COUNTS);
    float*  esum    = (float*)(ws + WS_ESUM);
    double* lossacc = (double*)(ws + WS_LOSS);
    float*  nws     = (float*)(ws + WS_NSUM);

    hipMemsetAsync(ws + ZERO_OFF, 0, ZERO_LEN, stream);

    enorm_kernel<<<N_, 64, 0, stream>>>(embed, enorm);
    transpose_kernel<<<Bb * Hh, 256, 0, stream>>>(z_e, flat, out + O_ZE);
    nn_kernel<<<dim3(M_ / 256, SPLITS), 256, 0, stream>>>(flat, embed, enorm, pscore, pidx);
    reduce_idx_kernel<<<M_ / 256, 256, 0, stream>>>(pscore, pidx, idxws, out + O_IDX);
    gather_kernel<<<(M_ * K_) / 256, 256, 0, stream>>>(z_e, embed, idxws,
                                                       out + O_ZQST, out + O_ZQ, lossacc);
    scatter_kernel<<<(M_ * K_) / 256, 256, 0, stream>>>(flat, idxws, esum, counts);
    ema_a_kernel<<<1, 1024, 0, stream>>>(cluster_size, counts, out + O_NCS, nws,
                                         lossacc, out + O_LOSS);
    ema_b_kernel<<<(N_ * K_) / 256, 256, 0, stream>>>(embed_avg, esum, out + O_NCS, nws,
                                                      out + O_NEA, out + O_EMB);
}

// Round 3
// 221.879 us; speedup vs baseline: 9.0915x; 2.1358x over previous
//
#include <hip/hip_runtime.h>

#define DECAY 0.99f
#define ONE_MINUS_DECAY 0.01f
#define EPSF 1e-5f
#define BETA 0.25f

constexpr int Bb = 32, Cc = 128, Hh = 32, Ww = 32;
constexpr int M_ = Bb * Hh * Ww;     // 32768 rows
constexpr int N_ = 1024;             // codes
constexpr int K_ = 128;              // dim
constexpr int SPLITS = 4;            // code splits (blockIdx.y), 256 codes each

// nn tiling
constexpr int BM = 128;              // rows per block
constexpr int BN = 256;              // codes per block (= N_/SPLITS)
constexpr int KT = 32;               // k-tile staged in LDS
constexpr int TM = 8, TN = 8;        // per-thread tile (codes strided by 32)
constexpr int XPAD = 132;            // xT row stride (16B-aligned rows, low write conflict)
constexpr int EPAD = 257;            // eT row stride (conflict-free lane-consecutive reads)

// ---- workspace layout (bytes) ----
constexpr size_t WS_FLAT   = 0;                                   // M_*K_ floats (16 MB)
constexpr size_t WS_PSCORE = WS_FLAT   + (size_t)M_ * K_ * 4;     // SPLITS*M_ floats
constexpr size_t WS_PIDX   = WS_PSCORE + (size_t)SPLITS * M_ * 4;
constexpr size_t WS_IDX    = WS_PIDX   + (size_t)SPLITS * M_ * 4; // M_ ints
constexpr size_t WS_ENORM  = WS_IDX    + (size_t)M_ * 4;          // N_ floats
constexpr size_t WS_COUNTS = WS_ENORM  + (size_t)N_ * 4;          // N_ ints      (zeroed)
constexpr size_t WS_ESUM   = WS_COUNTS + (size_t)N_ * 4;          // N_*K_ floats (zeroed)
constexpr size_t WS_LPART  = WS_ESUM   + (size_t)N_ * K_ * 4;     // 16384 doubles (written each call)
constexpr size_t WS_NSUM   = WS_LPART  + (size_t)16384 * 8;       // 1 float (written each call)
constexpr size_t ZERO_OFF  = WS_COUNTS;
constexpr size_t ZERO_LEN  = WS_ESUM + (size_t)N_ * K_ * 4 - WS_COUNTS;

// ---- output layout (float elements) ----
constexpr size_t O_ZQST = 0;
constexpr size_t O_LOSS = O_ZQST + (size_t)M_ * K_;   // 4194304
constexpr size_t O_IDX  = O_LOSS + 1;
constexpr size_t O_ZQ   = O_IDX  + (size_t)M_;
constexpr size_t O_ZE   = O_ZQ   + (size_t)M_ * K_;
constexpr size_t O_EMB  = O_ZE   + (size_t)M_ * K_;
constexpr size_t O_NCS  = O_EMB  + (size_t)N_ * K_;
constexpr size_t O_NEA  = O_NCS  + (size_t)N_;

// ||e_j||^2
__global__ void enorm_kernel(const float* __restrict__ embed, float* __restrict__ enorm) {
    int j = blockIdx.x;
    int lane = threadIdx.x;                    // 64 threads
    const float* e = embed + (size_t)j * K_;
    float a = e[lane], b = e[lane + 64];
    float s = a * a + b * b;
    #pragma unroll
    for (int off = 32; off; off >>= 1) s += __shfl_down(s, off);
    if (lane == 0) enorm[j] = s;
}

// (B,C,H,W) -> flat[r=b*1024+h*32+w][c], plus z_e passthrough output
__global__ void transpose_kernel(const float* __restrict__ ze,
                                 float* __restrict__ flat,
                                 float* __restrict__ out_ze) {
    __shared__ float tile[128][33];            // +1 pad breaks bank conflicts
    int b = blockIdx.x >> 5, h = blockIdx.x & 31;
    const size_t base = (size_t)b * 131072 + (size_t)h * 32;
    int t = threadIdx.x;                       // 256 threads
    #pragma unroll
    for (int i = 0; i < 16; ++i) {
        int q = i * 256 + t;                   // 4096 elements: c=q>>5, w=q&31
        int c = q >> 5, w = q & 31;
        float v = ze[base + (size_t)c * 1024 + w];
        tile[c][w] = v;
        out_ze[base + (size_t)c * 1024 + w] = v;
    }
    __syncthreads();
    float* dst = flat + ((size_t)b * 1024 + (size_t)h * 32) * K_;
    #pragma unroll
    for (int i = 0; i < 16; ++i) {
        int q = i * 256 + t;                   // c=q&127 contiguous per lane
        int c = q & 127, w = q >> 7;
        dst[(size_t)w * K_ + c] = tile[c][w];
    }
}

// Register-blocked NN search: 128 rows x 256 codes per block, 512 threads,
// each thread an 8x8 tile (codes strided by 32 -> conflict-free LDS reads).
struct SMain {
    float xT[KT][XPAD];   // transposed x tile  [k][row]
    float eT[KT][EPAD];   // transposed e tile  [k][code]
    float nl[BN];         // ||e||^2 for this code slice
};
struct SRed {
    float sc[BM][33];
    int   ic[BM][33];
};
union SU { SMain m; SRed r; };

__global__ __launch_bounds__(512, 1)
void nn_kernel(const float* __restrict__ flat,
               const float* __restrict__ embed,
               const float* __restrict__ enorm,
               float* __restrict__ pscore, int* __restrict__ pidx) {
    __shared__ SU u;
    const int t  = threadIdx.x;                // 512 threads
    const int tr = t >> 5;                     // 0..15 : row group (8 rows)
    const int tc = t & 31;                     // 0..31 : code lane
    const int r0 = blockIdx.x * BM;
    const int split = blockIdx.y;
    const int c0 = split * BN;

    if (t < BN) u.m.nl[t] = enorm[c0 + t];

    float acc[TM][TN];
    #pragma unroll
    for (int i = 0; i < TM; ++i)
        #pragma unroll
        for (int j = 0; j < TN; ++j) acc[i][j] = 0.f;

    for (int kt = 0; kt < K_ / KT; ++kt) {
        const int k0 = kt * KT;
        __syncthreads();                       // previous tile consumed / nl written
        // stage x tile: 128 rows x 32 ks = 1024 float4, 2 per thread
        #pragma unroll
        for (int i = 0; i < 2; ++i) {
            int q = i * 512 + t;
            int r = q >> 3, kq = q & 7;        // 8 float4 per row
            float4 v = *(const float4*)(flat + (size_t)(r0 + r) * K_ + k0 + kq * 4);
            u.m.xT[kq * 4 + 0][r] = v.x;
            u.m.xT[kq * 4 + 1][r] = v.y;
            u.m.xT[kq * 4 + 2][r] = v.z;
            u.m.xT[kq * 4 + 3][r] = v.w;
        }
        // stage e tile: 256 codes x 32 ks = 2048 float4, 4 per thread
        #pragma unroll
        for (int i = 0; i < 4; ++i) {
            int q = i * 512 + t;
            int c = q >> 3, kq = q & 7;
            float4 v = *(const float4*)(embed + (size_t)(c0 + c) * K_ + k0 + kq * 4);
            u.m.eT[kq * 4 + 0][c] = v.x;
            u.m.eT[kq * 4 + 1][c] = v.y;
            u.m.eT[kq * 4 + 2][c] = v.z;
            u.m.eT[kq * 4 + 3][c] = v.w;
        }
        __syncthreads();
        #pragma unroll 4
        for (int k = 0; k < KT; ++k) {
            float4 xa = *(const float4*)&u.m.xT[k][tr * 8];      // b128, broadcast
            float4 xb = *(const float4*)&u.m.xT[k][tr * 8 + 4];
            float xv[TM] = {xa.x, xa.y, xa.z, xa.w, xb.x, xb.y, xb.z, xb.w};
            float ev[TN];
            #pragma unroll
            for (int j = 0; j < TN; ++j) ev[j] = u.m.eT[k][tc + 32 * j];
            #pragma unroll
            for (int i = 0; i < TM; ++i)
                #pragma unroll
                for (int j = 0; j < TN; ++j)
                    acc[i][j] = fmaf(xv[i], ev[j], acc[i][j]);
        }
    }

    // per-thread argmin (codes ascend with j -> strict < keeps first min)
    float bsc[TM]; int bix[TM];
    #pragma unroll
    for (int i = 0; i < TM; ++i) { bsc[i] = 3.4e38f; bix[i] = 0; }
    #pragma unroll
    for (int j = 0; j < TN; ++j) {
        int c = tc + 32 * j;
        float en = u.m.nl[c];
        #pragma unroll
        for (int i = 0; i < TM; ++i) {
            float s = fmaf(-2.f, acc[i][j], en);
            if (s < bsc[i]) { bsc[i] = s; bix[i] = c0 + c; }
        }
    }
    __syncthreads();                           // done reading u.m
    #pragma unroll
    for (int i = 0; i < TM; ++i) {
        u.r.sc[tr * 8 + i][tc] = bsc[i];
        u.r.ic[tr * 8 + i][tc] = bix[i];
    }
    __syncthreads();
    if (t < BM) {
        float best = u.r.sc[t][0];
        int bj = u.r.ic[t][0];
        for (int c = 1; c < 32; ++c) {
            float v = u.r.sc[t][c];
            int j = u.r.ic[t][c];
            if (v < best || (v == best && j < bj)) { best = v; bj = j; }
        }
        pscore[(size_t)split * M_ + r0 + t] = best;
        pidx[(size_t)split * M_ + r0 + t] = bj;
    }
}

__global__ void reduce_idx_kernel(const float* __restrict__ pscore,
                                  const int* __restrict__ pidx,
                                  int* __restrict__ idxws, float* __restrict__ out_idx) {
    int r = blockIdx.x * 256 + threadIdx.x;
    float best = pscore[r];
    int bj = pidx[r];
    #pragma unroll
    for (int s = 1; s < SPLITS; ++s) {
        float v = pscore[(size_t)s * M_ + r];
        int j = pidx[(size_t)s * M_ + r];
        if (v < best) { best = v; bj = j; }   // ascending split => first-min wins
    }
    idxws[r] = bj;
    out_idx[r] = (float)bj;
}

// output-layout gather: z_q_st, z_q, per-block loss partial (no atomics)
__global__ void gather_kernel(const float* __restrict__ ze,
                              const float* __restrict__ embed,
                              const int* __restrict__ idxws,
                              float* __restrict__ out_st, float* __restrict__ out_zq,
                              double* __restrict__ lpart) {
    int o = blockIdx.x * 256 + threadIdx.x;
    int w = o & 31, h = (o >> 5) & 31, c = (o >> 10) & 127, b = o >> 17;
    int r = b * 1024 + h * 32 + w;
    int j = idxws[r];
    float zq = embed[(size_t)j * K_ + c];
    float zev = ze[o];
    float st = zev + (zq - zev);              // match reference rounding
    out_st[o] = st;
    out_zq[o] = zq;
    float diff = st - zev;
    __shared__ double red[256];
    red[threadIdx.x] = (double)diff * (double)diff;
    __syncthreads();
    for (int s = 128; s; s >>= 1) {
        if (threadIdx.x < s) red[threadIdx.x] += red[threadIdx.x + s];
        __syncthreads();
    }
    if (threadIdx.x == 0) lpart[blockIdx.x] = red[0];
}

// embed_sum scatter + counts
__global__ void scatter_kernel(const float* __restrict__ flat,
                               const int* __restrict__ idxws,
                               float* __restrict__ esum, int* __restrict__ counts) {
    int o = blockIdx.x * 256 + threadIdx.x;
    int r = o >> 7, k = o & 127;
    int j = idxws[r];
    atomicAdd(esum + (size_t)j * K_ + k, flat[o]);
    if (k == 0) atomicAdd(counts + j, 1);
}

__global__ void ema_a_kernel(const float* __restrict__ cluster_size,
                             const int* __restrict__ counts,
                             float* __restrict__ out_ncs, float* __restrict__ nws,
                             const double* __restrict__ lpart, float* __restrict__ out_loss) {
    int j = threadIdx.x;                       // 1024 threads
    float ncs = cluster_size[j] * DECAY + ONE_MINUS_DECAY * (float)counts[j];
    out_ncs[j] = ncs;
    __shared__ float red[1024];
    __shared__ double dred[1024];
    red[j] = ncs;
    double s = 0.0;
    #pragma unroll
    for (int i = 0; i < 16; ++i) s += lpart[j * 16 + i];
    dred[j] = s;
    __syncthreads();
    for (int st = 512; st; st >>= 1) {
        if (j < st) { red[j] += red[j + st]; dred[j] += dred[j + st]; }
        __syncthreads();
    }
    if (j == 0) {
        nws[0] = red[0];
        out_loss[0] = (float)((double)BETA * (dred[0] / 4194304.0));
    }
}

__global__ void ema_b_kernel(const float* __restrict__ embed_avg,
                             const float* __restrict__ esum,
                             const float* __restrict__ out_ncs,
                             const float* __restrict__ nws,
                             float* __restrict__ out_nea, float* __restrict__ out_emb) {
    int o = blockIdx.x * 256 + threadIdx.x;
    int j = o >> 7;
    float navg = embed_avg[o] * DECAY + ONE_MINUS_DECAY * esum[o];
    out_nea[o] = navg;
    float n = nws[0];
    float denom = n + 1024.0f * EPSF;
    float cs = (out_ncs[j] + EPSF) / denom * n;
    float cs_safe = fmaxf(cs, EPSF);
    float v = navg / cs_safe;
    if (v != v) v = 0.f;                       // nan_to_num
    v = fminf(fmaxf(v, -2.f), 2.f);            // clip
    out_emb[o] = v;
}

extern "C" void kernel_launch(void* const* d_in, const int* in_sizes, int n_in,
                              void* d_out, int out_size, void* d_ws, size_t ws_size,
                              hipStream_t stream) {
    const float* z_e          = (const float*)d_in[0];
    const float* embed        = (const float*)d_in[1];
    const float* cluster_size = (const float*)d_in[2];
    const float* embed_avg    = (const float*)d_in[3];
    float* out = (float*)d_out;
    char*  ws  = (char*)d_ws;

    float*  flat    = (float*)(ws + WS_FLAT);
    float*  pscore  = (float*)(ws + WS_PSCORE);
    int*    pidx    = (int*)  (ws + WS_PIDX);
    int*    idxws   = (int*)  (ws + WS_IDX);
    float*  enorm   = (float*)(ws + WS_ENORM);
    int*    counts  = (int*)  (ws + WS_COUNTS);
    float*  esum    = (float*)(ws + WS_ESUM);
    double* lpart   = (double*)(ws + WS_LPART);
    float*  nws     = (float*)(ws + WS_NSUM);

    hipMemsetAsync(ws + ZERO_OFF, 0, ZERO_LEN, stream);

    enorm_kernel<<<N_, 64, 0, stream>>>(embed, enorm);
    transpose_kernel<<<Bb * Hh, 256, 0, stream>>>(z_e, flat, out + O_ZE);
    nn_kernel<<<dim3(M_ / BM, SPLITS), 512, 0, stream>>>(flat, embed, enorm, pscore, pidx);
    reduce_idx_kernel<<<M_ / 256, 256, 0, stream>>>(pscore, pidx, idxws, out + O_IDX);
    gather_kernel<<<(M_ * K_) / 256, 256, 0, stream>>>(z_e, embed, idxws,
                                                       out + O_ZQST, out + O_ZQ, lpart);
    scatter_kernel<<<(M_ * K_) / 256, 256, 0, stream>>>(flat, idxws, esum, counts);
    ema_a_kernel<<<1, 1024, 0, stream>>>(cluster_size, counts, out + O_NCS, nws,
                                         lpart, out + O_LOSS);
    ema_b_kernel<<<(N_ * K_) / 256, 256, 0, stream>>>(embed_avg, esum, out + O_NCS, nws,
                                                      out + O_NEA, out + O_EMB);
}

// Round 4
// 142.481 us; speedup vs baseline: 14.1578x; 1.5573x over previous
//
#include <hip/hip_runtime.h>

#define DECAY 0.99f
#define ONE_MINUS_DECAY 0.01f
#define EPSF 1e-5f
#define BETA 0.25f
#define TAU 1e-2f

constexpr int Bb = 32, Hh = 32;
constexpr int M_ = 32768;            // rows (B*H*W)
constexpr int N_ = 1024;             // codes
constexpr int K_ = 128;              // dim

typedef _Float16 f16;
typedef f16 f16x8 __attribute__((ext_vector_type(8)));
typedef float f32x4 __attribute__((ext_vector_type(4)));

// ---- workspace layout (bytes) ----
constexpr size_t WS_FLAT   = 0;                                   // M*K fp32 (16MB)
constexpr size_t WS_EH     = WS_FLAT   + (size_t)M_ * K_ * 4;     // N*K f16 (-2e hi)
constexpr size_t WS_EL     = WS_EH     + (size_t)N_ * K_ * 2;     // N*K f16 (-2e lo)
constexpr size_t WS_NL     = WS_EL     + (size_t)N_ * K_ * 2;     // N fp32 ||e||^2
constexpr size_t WS_P1     = WS_NL     + (size_t)N_ * 4;          // 16*M f32 best score
constexpr size_t WS_PI1    = WS_P1     + (size_t)16 * M_ * 4;     // 16*M int best idx
constexpr size_t WS_P2     = WS_PI1    + (size_t)16 * M_ * 4;     // 16*M f32 2nd score
constexpr size_t WS_PI2    = WS_P2     + (size_t)16 * M_ * 4;     // 16*M int 2nd idx
constexpr size_t WS_IDX    = WS_PI2    + (size_t)16 * M_ * 4;     // M int
constexpr size_t WS_COUNTS = WS_IDX    + (size_t)M_ * 4;          // N int   (zeroed)
constexpr size_t WS_ESUM   = WS_COUNTS + (size_t)N_ * 4;          // N*K f32 (zeroed)
constexpr size_t WS_LPART  = WS_ESUM   + (size_t)N_ * K_ * 4;     // 16384 doubles
constexpr size_t WS_NSUM   = WS_LPART  + (size_t)16384 * 8;       // 1 float
constexpr size_t ZERO_OFF  = WS_COUNTS;
constexpr size_t ZERO_LEN  = WS_LPART - WS_COUNTS;

// ---- output layout (float elements) ----
constexpr size_t O_ZQST = 0;
constexpr size_t O_LOSS = O_ZQST + (size_t)M_ * K_;
constexpr size_t O_IDX  = O_LOSS + 1;
constexpr size_t O_ZQ   = O_IDX  + (size_t)M_;
constexpr size_t O_ZE   = O_ZQ   + (size_t)M_ * K_;
constexpr size_t O_EMB  = O_ZE   + (size_t)M_ * K_;
constexpr size_t O_NCS  = O_EMB  + (size_t)N_ * K_;
constexpr size_t O_NEA  = O_NCS  + (size_t)N_;

// ||e||^2 + hi/lo fp16 split of (-2e)
__global__ void ecvt_kernel(const float* __restrict__ embed,
                            f16* __restrict__ eh, f16* __restrict__ el,
                            float* __restrict__ nl) {
    int j = blockIdx.x, lane = threadIdx.x;          // 64 threads
    const float* e = embed + (size_t)j * K_;
    float a = e[lane], b = e[lane + 64];
    float s = a * a + b * b;
    #pragma unroll
    for (int off = 32; off; off >>= 1) s += __shfl_down(s, off);
    if (lane == 0) nl[j] = s;
    float ma = -2.f * a, mb = -2.f * b;
    f16 ah = (f16)ma, bh2 = (f16)mb;
    eh[(size_t)j * K_ + lane] = ah;
    eh[(size_t)j * K_ + lane + 64] = bh2;
    el[(size_t)j * K_ + lane] = (f16)(ma - (float)ah);
    el[(size_t)j * K_ + lane + 64] = (f16)(mb - (float)bh2);
}

// (B,C,H,W) -> flat[r][c], plus z_e passthrough output
__global__ void transpose_kernel(const float* __restrict__ ze,
                                 float* __restrict__ flat,
                                 float* __restrict__ out_ze) {
    __shared__ float tile[128][33];
    int b = blockIdx.x >> 5, h = blockIdx.x & 31;
    const size_t base = (size_t)b * 131072 + (size_t)h * 32;
    int t = threadIdx.x;
    #pragma unroll
    for (int i = 0; i < 16; ++i) {
        int q = i * 256 + t;
        int c = q >> 5, w = q & 31;
        float v = ze[base + (size_t)c * 1024 + w];
        tile[c][w] = v;
        out_ze[base + (size_t)c * 1024 + w] = v;
    }
    __syncthreads();
    float* dst = flat + ((size_t)b * 1024 + (size_t)h * 32) * K_;
    #pragma unroll
    for (int i = 0; i < 16; ++i) {
        int q = i * 256 + t;
        int c = q & 127, w = q >> 7;
        dst[(size_t)w * K_ + c] = tile[c][w];
    }
}

// MFMA NN search. Grid (128, 4): blockIdx.y = 256-code split; 4 waves each own
// 64 codes held as persistent A-fragments (fp16 hi+lo of -2e). x staged in LDS
// (64 rows, XOR-swizzled), B-frags shared across the wave's 4 code mtiles.
// Distances d = ||e||^2 - 2 x.e via 3 MFMAs (xh*eh + xh*el + xl*eh), fp32 acc.
// Per-row top-2 tracked; near-ties refined exactly later.
__global__ __launch_bounds__(256, 2)
void nn_kernel(const float* __restrict__ flat, const f16* __restrict__ eh,
               const f16* __restrict__ el, const float* __restrict__ nl,
               float* __restrict__ p1, int* __restrict__ pi1,
               float* __restrict__ p2, int* __restrict__ pi2) {
    __shared__ f16 xh_t[64 * 128];
    __shared__ f16 xl_t[64 * 128];
    const int t = threadIdx.x;
    const int wave = t >> 6, lane = t & 63;
    const int crow = lane & 15, g = lane >> 4;
    const int c0 = blockIdx.y * 256 + wave * 64;

    f16x8 efh[4][4], efl[4][4];          // [code-mtile][ktile] : 128 VGPR
    #pragma unroll
    for (int m = 0; m < 4; ++m)
        #pragma unroll
        for (int kt = 0; kt < 4; ++kt) {
            size_t eo = (size_t)(c0 + m * 16 + crow) * K_ + kt * 32 + g * 8;
            efh[m][kt] = *(const f16x8*)(eh + eo);
            efl[m][kt] = *(const f16x8*)(el + eo);
        }
    f32x4 nlv[4];
    #pragma unroll
    for (int m = 0; m < 4; ++m)
        nlv[m] = *(const f32x4*)(nl + c0 + m * 16 + g * 4);

    for (int bt = 0; bt < 4; ++bt) {
        const int R0 = (blockIdx.x * 4 + bt) * 64;
        __syncthreads();
        // stage 64 rows fp32 -> f16 hi/lo, swizzled (idx ^= (row&15)*8 halves)
        #pragma unroll
        for (int p = 0; p < 4; ++p) {
            int row = p * 16 + (t >> 4);
            int k8 = (t & 15) * 8;
            const float* src = flat + (size_t)(R0 + row) * K_ + k8;
            float4 v0 = *(const float4*)src;
            float4 v1 = *(const float4*)(src + 4);
            float vv[8] = {v0.x, v0.y, v0.z, v0.w, v1.x, v1.y, v1.z, v1.w};
            f16x8 hv, lv;
            #pragma unroll
            for (int i = 0; i < 8; ++i) {
                f16 h = (f16)vv[i];
                hv[i] = h;
                lv[i] = (f16)(vv[i] - (float)h);
            }
            int idx = row * 128 + (k8 ^ ((row & 15) * 8));
            *(f16x8*)&xh_t[idx] = hv;
            *(f16x8*)&xl_t[idx] = lv;
        }
        __syncthreads();
        #pragma unroll
        for (int st = 0; st < 4; ++st) {
            f32x4 acc[4];
            #pragma unroll
            for (int m = 0; m < 4; ++m) acc[m] = (f32x4){0.f, 0.f, 0.f, 0.f};
            #pragma unroll
            for (int kt = 0; kt < 4; ++kt) {
                int off = (st * 16 + crow) * 128 + ((kt * 32 + g * 8) ^ (crow * 8));
                f16x8 bh = *(const f16x8*)&xh_t[off];
                f16x8 bl = *(const f16x8*)&xl_t[off];
                #pragma unroll
                for (int m = 0; m < 4; ++m) {
                    acc[m] = __builtin_amdgcn_mfma_f32_16x16x32_f16(efh[m][kt], bh, acc[m], 0, 0, 0);
                    acc[m] = __builtin_amdgcn_mfma_f32_16x16x32_f16(efl[m][kt], bh, acc[m], 0, 0, 0);
                    acc[m] = __builtin_amdgcn_mfma_f32_16x16x32_f16(efh[m][kt], bl, acc[m], 0, 0, 0);
                }
            }
            // top-2 fold: lane's col = one x-row; codes ascend in (m,q)
            float b1 = 3.4e38f, b2 = 3.4e38f; int i1 = -1, i2 = -1;
            #pragma unroll
            for (int m = 0; m < 4; ++m)
                #pragma unroll
                for (int q = 0; q < 4; ++q) {
                    float s = acc[m][q] + nlv[m][q];
                    int c = c0 + m * 16 + g * 4 + q;
                    if (s < b1) { b2 = b1; i2 = i1; b1 = s; i1 = c; }
                    else if (s < b2 || (s == b2 && c < i2)) { b2 = s; i2 = c; }
                }
            #pragma unroll
            for (int d = 16; d <= 32; d <<= 1) {
                float ob1 = __shfl_xor(b1, d); int oi1 = __shfl_xor(i1, d);
                float ob2 = __shfl_xor(b2, d); int oi2 = __shfl_xor(i2, d);
                bool o_lt = (ob1 < b1) || (ob1 == b1 && oi1 < i1);
                float w2 = o_lt ? ob2 : b2; int wi2 = o_lt ? oi2 : i2;
                float l1 = o_lt ? b1 : ob1; int li1 = o_lt ? i1 : oi1;
                if (o_lt) { b1 = ob1; i1 = oi1; }
                bool s_lt = (l1 < w2) || (l1 == w2 && li1 < wi2);
                b2 = s_lt ? l1 : w2; i2 = s_lt ? li1 : wi2;
            }
            if (lane < 16) {
                size_t o = (size_t)(blockIdx.y * 4 + wave) * M_ + R0 + st * 16 + crow;
                p1[o] = b1; pi1[o] = i1; p2[o] = b2; pi2[o] = i2;
            }
        }
    }
}

// merge 16 wave-partials; exact fp32 refine of near-ties (b2-b1 < TAU)
__global__ void reduce_refine_kernel(const float* __restrict__ p1, const int* __restrict__ pi1,
                                     const float* __restrict__ p2, const int* __restrict__ pi2,
                                     const float* __restrict__ flat, const float* __restrict__ embed,
                                     const float* __restrict__ nl,
                                     int* __restrict__ idxws, float* __restrict__ out_idx) {
    int r = blockIdx.x * 256 + threadIdx.x;
    float b1 = 3.4e38f, b2 = 3.4e38f; int i1 = -1, i2 = -1;
    for (int s = 0; s < 16; ++s) {
        size_t o = (size_t)s * M_ + r;
        float ob1 = p1[o]; int oi1 = pi1[o];
        float ob2 = p2[o]; int oi2 = pi2[o];
        bool o_lt = (ob1 < b1) || (ob1 == b1 && oi1 < i1);
        float w2 = o_lt ? ob2 : b2; int wi2 = o_lt ? oi2 : i2;
        float l1 = o_lt ? b1 : ob1; int li1 = o_lt ? i1 : oi1;
        if (o_lt) { b1 = ob1; i1 = oi1; }
        bool s_lt = (l1 < w2) || (l1 == w2 && li1 < wi2);
        b2 = s_lt ? l1 : w2; i2 = s_lt ? li1 : wi2;
    }
    if (b2 - b1 < TAU) {
        const float* x  = flat  + (size_t)r * K_;
        const float* ea = embed + (size_t)i1 * K_;
        const float* eb = embed + (size_t)i2 * K_;
        float da = 0.f, db = 0.f;
        for (int k = 0; k < K_; ++k) { da = fmaf(x[k], ea[k], da); db = fmaf(x[k], eb[k], db); }
        float s1 = fmaf(-2.f, da, nl[i1]);
        float s2 = fmaf(-2.f, db, nl[i2]);
        if (s2 < s1 || (s2 == s1 && i2 < i1)) i1 = i2;
    }
    idxws[r] = i1;
    out_idx[r] = (float)i1;
}

__global__ void gather_kernel(const float* __restrict__ ze,
                              const float* __restrict__ embed,
                              const int* __restrict__ idxws,
                              float* __restrict__ out_st, float* __restrict__ out_zq,
                              double* __restrict__ lpart) {
    int o = blockIdx.x * 256 + threadIdx.x;
    int w = o & 31, h = (o >> 5) & 31, c = (o >> 10) & 127, b = o >> 17;
    int r = b * 1024 + h * 32 + w;
    int j = idxws[r];
    float zq = embed[(size_t)j * K_ + c];
    float zev = ze[o];
    float st = zev + (zq - zev);
    out_st[o] = st;
    out_zq[o] = zq;
    float diff = st - zev;
    __shared__ double red[256];
    red[threadIdx.x] = (double)diff * (double)diff;
    __syncthreads();
    for (int s = 128; s; s >>= 1) {
        if (threadIdx.x < s) red[threadIdx.x] += red[threadIdx.x + s];
        __syncthreads();
    }
    if (threadIdx.x == 0) lpart[blockIdx.x] = red[0];
}

__global__ void scatter_kernel(const float* __restrict__ flat,
                               const int* __restrict__ idxws,
                               float* __restrict__ esum, int* __restrict__ counts) {
    int o = blockIdx.x * 256 + threadIdx.x;
    int r = o >> 7, k = o & 127;
    int j = idxws[r];
    atomicAdd(esum + (size_t)j * K_ + k, flat[o]);
    if (k == 0) atomicAdd(counts + j, 1);
}

__global__ void ema_a_kernel(const float* __restrict__ cluster_size,
                             const int* __restrict__ counts,
                             float* __restrict__ out_ncs, float* __restrict__ nws,
                             const double* __restrict__ lpart, float* __restrict__ out_loss) {
    int j = threadIdx.x;                       // 1024 threads
    float ncs = cluster_size[j] * DECAY + ONE_MINUS_DECAY * (float)counts[j];
    out_ncs[j] = ncs;
    __shared__ float red[1024];
    __shared__ double dred[1024];
    red[j] = ncs;
    double s = 0.0;
    #pragma unroll
    for (int i = 0; i < 16; ++i) s += lpart[j * 16 + i];
    dred[j] = s;
    __syncthreads();
    for (int st = 512; st; st >>= 1) {
        if (j < st) { red[j] += red[j + st]; dred[j] += dred[j + st]; }
        __syncthreads();
    }
    if (j == 0) {
        nws[0] = red[0];
        out_loss[0] = (float)((double)BETA * (dred[0] / 4194304.0));
    }
}

__global__ void ema_b_kernel(const float* __restrict__ embed_avg,
                             const float* __restrict__ esum,
                             const float* __restrict__ out_ncs,
                             const float* __restrict__ nws,
                             float* __restrict__ out_nea, float* __restrict__ out_emb) {
    int o = blockIdx.x * 256 + threadIdx.x;
    int j = o >> 7;
    float navg = embed_avg[o] * DECAY + ONE_MINUS_DECAY * esum[o];
    out_nea[o] = navg;
    float n = nws[0];
    float denom = n + 1024.0f * EPSF;
    float cs = (out_ncs[j] + EPSF) / denom * n;
    float cs_safe = fmaxf(cs, EPSF);
    float v = navg / cs_safe;
    if (v != v) v = 0.f;
    v = fminf(fmaxf(v, -2.f), 2.f);
    out_emb[o] = v;
}

extern "C" void kernel_launch(void* const* d_in, const int* in_sizes, int n_in,
                              void* d_out, int out_size, void* d_ws, size_t ws_size,
                              hipStream_t stream) {
    const float* z_e          = (const float*)d_in[0];
    const float* embed        = (const float*)d_in[1];
    const float* cluster_size = (const float*)d_in[2];
    const float* embed_avg    = (const float*)d_in[3];
    float* out = (float*)d_out;
    char*  ws  = (char*)d_ws;

    float*  flat   = (float*)(ws + WS_FLAT);
    f16*    ehp    = (f16*)  (ws + WS_EH);
    f16*    elp    = (f16*)  (ws + WS_EL);
    float*  nlp    = (float*)(ws + WS_NL);
    float*  p1     = (float*)(ws + WS_P1);
    int*    pi1    = (int*)  (ws + WS_PI1);
    float*  p2     = (float*)(ws + WS_P2);
    int*    pi2    = (int*)  (ws + WS_PI2);
    int*    idxws  = (int*)  (ws + WS_IDX);
    int*    counts = (int*)  (ws + WS_COUNTS);
    float*  esum   = (float*)(ws + WS_ESUM);
    double* lpart  = (double*)(ws + WS_LPART);
    float*  nws    = (float*)(ws + WS_NSUM);

    hipMemsetAsync(ws + ZERO_OFF, 0, ZERO_LEN, stream);

    ecvt_kernel<<<N_, 64, 0, stream>>>(embed, ehp, elp, nlp);
    transpose_kernel<<<Bb * Hh, 256, 0, stream>>>(z_e, flat, out + O_ZE);
    nn_kernel<<<dim3(128, 4), 256, 0, stream>>>(flat, ehp, elp, nlp, p1, pi1, p2, pi2);
    reduce_refine_kernel<<<M_ / 256, 256, 0, stream>>>(p1, pi1, p2, pi2, flat, embed, nlp,
                                                       idxws, out + O_IDX);
    gather_kernel<<<(M_ * K_) / 256, 256, 0, stream>>>(z_e, embed, idxws,
                                                       out + O_ZQST, out + O_ZQ, lpart);
    scatter_kernel<<<(M_ * K_) / 256, 256, 0, stream>>>(flat, idxws, esum, counts);
    ema_a_kernel<<<1, 1024, 0, stream>>>(cluster_size, counts, out + O_NCS, nws,
                                         lpart, out + O_LOSS);
    ema_b_kernel<<<(N_ * K_) / 256, 256, 0, stream>>>(embed_avg, esum, out + O_NCS, nws,
                                                      out + O_NEA, out + O_EMB);
}